// Round 1
// baseline (409.908 us; speedup 1.0000x reference)
//
#include <hip/hip_runtime.h>

// 8-qubit statevector simulator, one wave (64 lanes) per batch element.
// State: 256 complex amplitudes = 64 lanes x 4 regs; index i = (r<<6)|lane.
// Wire w <-> bit (7-w). Bits 0-5 live in the lane id (cross-lane via shfl_xor),
// bits 6-7 live in the register index (pure FMA, no shuffle).

struct c32 { float x, y; };

__device__ __forceinline__ c32 shfl_xor_c(c32 v, int mask) {
    c32 r;
    r.x = __shfl_xor(v.x, mask, 64);
    r.y = __shfl_xor(v.y, mask, 64);
    return r;
}

// n = ga*a + gp*p (complex fused)
__device__ __forceinline__ c32 cmadd2(c32 ga, c32 a, c32 gp, c32 p) {
    c32 n;
    n.x = ga.x * a.x - ga.y * a.y + gp.x * p.x - gp.y * p.y;
    n.y = ga.x * a.y + ga.y * a.x + gp.x * p.y + gp.y * p.x;
    return n;
}

// RX mix: n = c*a - i*s*p  (RX matrix is symmetric, same formula both pair roles)
__device__ __forceinline__ c32 rx_mix(float c, float s, c32 a, c32 p) {
    c32 n;
    n.x = c * a.x + s * p.y;
    n.y = c * a.y - s * p.x;
    return n;
}

__device__ __forceinline__ void apply_rx(c32 st[4], int lane, int bb, float c, float s) {
    if (bb < 6) {
#pragma unroll
        for (int r = 0; r < 4; ++r) {
            c32 p = shfl_xor_c(st[r], 1 << bb);
            st[r] = rx_mix(c, s, st[r], p);
        }
    } else if (bb == 6) {
        c32 n0 = rx_mix(c, s, st[0], st[1]);
        c32 n1 = rx_mix(c, s, st[1], st[0]);
        c32 n2 = rx_mix(c, s, st[2], st[3]);
        c32 n3 = rx_mix(c, s, st[3], st[2]);
        st[0] = n0; st[1] = n1; st[2] = n2; st[3] = n3;
    } else {
        c32 n0 = rx_mix(c, s, st[0], st[2]);
        c32 n2 = rx_mix(c, s, st[2], st[0]);
        c32 n1 = rx_mix(c, s, st[1], st[3]);
        c32 n3 = rx_mix(c, s, st[3], st[1]);
        st[0] = n0; st[1] = n1; st[2] = n2; st[3] = n3;
    }
}

__device__ __forceinline__ void apply_rot(c32 st[4], int lane, int bb,
                                          c32 g00, c32 g01, c32 g10, c32 g11) {
    if (bb < 6) {
#pragma unroll
        for (int r = 0; r < 4; ++r) {
            c32 p = shfl_xor_c(st[r], 1 << bb);
            bool hi = (lane >> bb) & 1;
            c32 ga, gp;
            ga.x = hi ? g11.x : g00.x;
            ga.y = hi ? g11.y : g00.y;
            gp.x = hi ? g10.x : g01.x;
            gp.y = hi ? g10.y : g01.y;
            st[r] = cmadd2(ga, st[r], gp, p);
        }
    } else if (bb == 6) {
        c32 n0 = cmadd2(g00, st[0], g01, st[1]);
        c32 n1 = cmadd2(g10, st[0], g11, st[1]);
        c32 n2 = cmadd2(g00, st[2], g01, st[3]);
        c32 n3 = cmadd2(g10, st[2], g11, st[3]);
        st[0] = n0; st[1] = n1; st[2] = n2; st[3] = n3;
    } else {
        c32 n0 = cmadd2(g00, st[0], g01, st[2]);
        c32 n2 = cmadd2(g10, st[0], g11, st[2]);
        c32 n1 = cmadd2(g00, st[1], g01, st[3]);
        c32 n3 = cmadd2(g10, st[1], g11, st[3]);
        st[0] = n0; st[1] = n1; st[2] = n2; st[3] = n3;
    }
}

__device__ __forceinline__ void cswap(bool c, c32& a, c32& b) {
    c32 t = a;
    a.x = c ? b.x : a.x; a.y = c ? b.y : a.y;
    b.x = c ? t.x : b.x; b.y = c ? t.y : b.y;
}

__device__ __forceinline__ void apply_cnot(c32 st[4], int lane, int bc, int bt) {
    if (bt < 6) {
        if (bc < 6) {
            bool ctrl = (lane >> bc) & 1;
#pragma unroll
            for (int r = 0; r < 4; ++r) {
                c32 p = shfl_xor_c(st[r], 1 << bt);
                st[r].x = ctrl ? p.x : st[r].x;
                st[r].y = ctrl ? p.y : st[r].y;
            }
        } else {
            // control bit lives in the register index: only regs with that bit set move
#pragma unroll
            for (int r = 0; r < 4; ++r) {
                if ((r >> (bc - 6)) & 1) {
                    st[r] = shfl_xor_c(st[r], 1 << bt);
                }
            }
        }
    } else {
        if (bc < 6) {
            bool ctrl = (lane >> bc) & 1;
            if (bt == 6) { cswap(ctrl, st[0], st[1]); cswap(ctrl, st[2], st[3]); }
            else         { cswap(ctrl, st[0], st[2]); cswap(ctrl, st[1], st[3]); }
        } else {
            // both bits in the register index
            if (bc == 7 && bt == 6) { c32 t = st[2]; st[2] = st[3]; st[3] = t; }
            else if (bc == 6 && bt == 7) { c32 t = st[1]; st[1] = st[3]; st[3] = t; }
        }
    }
}

__global__ __launch_bounds__(256) void qsim_kernel(const float* __restrict__ x,
                                                   const float* __restrict__ theta,
                                                   float* __restrict__ out,
                                                   int batch) {
    // Per-block: compute the 16 batch-uniform Rot matrices into LDS.
    __shared__ float rot[2 * 8 * 8];
    const int t = threadIdx.x;
    if (t < 16) {
        const int l = t >> 3, w = t & 7;
        const float phi = theta[(l * 8 + w) * 3 + 0];
        const float th  = theta[(l * 8 + w) * 3 + 1];
        const float om  = theta[(l * 8 + w) * 3 + 2];
        const float c = cosf(0.5f * th), s = sinf(0.5f * th);
        const float p = 0.5f * (phi + om), m = 0.5f * (phi - om);
        const float cp = cosf(p), sp = sinf(p);
        const float cm = cosf(m), sm = sinf(m);
        float* g = &rot[t * 8];
        g[0] = c * cp;  g[1] = -c * sp;   // g00 = e^{-i p} c
        g[2] = -s * cm; g[3] = -s * sm;   // g01 = -e^{+i m} s
        g[4] = s * cm;  g[5] = -s * sm;   // g10 = e^{-i m} s
        g[6] = c * cp;  g[7] = c * sp;    // g11 = e^{+i p} c
    }
    __syncthreads();

    const int lane = t & 63;
    const int b = blockIdx.x * 4 + (t >> 6);
    if (b >= batch) return;  // wave-uniform branch (after the barrier)

    // Embedding angles: lanes 0..7 hold cos/sin of x[b,w]/2
    float c8 = 0.f, s8 = 0.f;
    if (lane < 8) {
        const float xv = 0.5f * x[b * 8 + lane];
        c8 = cosf(xv);
        s8 = sinf(xv);
    }

    c32 st[4];
#pragma unroll
    for (int r = 0; r < 4; ++r) { st[r].x = 0.f; st[r].y = 0.f; }
    if (lane == 0) st[0].x = 1.f;

    // AngleEmbedding: RX(x[b,w]) on wire w
#pragma unroll
    for (int w = 0; w < 8; ++w) {
        const float c = __shfl(c8, w, 64);
        const float s = __shfl(s8, w, 64);
        apply_rx(st, lane, 7 - w, c, s);
    }

    // StronglyEntanglingLayers
#pragma unroll
    for (int l = 0; l < 2; ++l) {
#pragma unroll
        for (int w = 0; w < 8; ++w) {
            const float* g = &rot[(l * 8 + w) * 8];
            c32 g00{g[0], g[1]}, g01{g[2], g[3]}, g10{g[4], g[5]}, g11{g[6], g[7]};
            apply_rot(st, lane, 7 - w, g00, g01, g10, g11);
        }
        const int rr = l + 1;  // PennyLane ranges: (l % 7) + 1
#pragma unroll
        for (int w = 0; w < 8; ++w) {
            const int tw = (w + rr) & 7;
            apply_cnot(st, lane, 7 - w, 7 - tw);
        }
    }

    // <Z0>: bit7 (register-index bit 1): regs 0,1 are +, regs 2,3 are -
    float v = st[0].x * st[0].x + st[0].y * st[0].y
            + st[1].x * st[1].x + st[1].y * st[1].y
            - st[2].x * st[2].x - st[2].y * st[2].y
            - st[3].x * st[3].x - st[3].y * st[3].y;
#pragma unroll
    for (int off = 32; off > 0; off >>= 1)
        v += __shfl_xor(v, off, 64);

    if (lane == 0) out[b] = (v + 1.f) * 0.5f;
}

extern "C" void kernel_launch(void* const* d_in, const int* in_sizes, int n_in,
                              void* d_out, int out_size, void* d_ws, size_t ws_size,
                              hipStream_t stream) {
    const float* x     = (const float*)d_in[0];
    const float* theta = (const float*)d_in[1];
    float* out = (float*)d_out;
    const int batch = in_sizes[0] / 8;          // 131072
    const int blocks = (batch + 3) / 4;         // 4 batch elems (waves) per block
    qsim_kernel<<<dim3(blocks), dim3(256), 0, stream>>>(x, theta, out, batch);
}

// Round 2
// 184.501 us; speedup vs baseline: 2.2217x; 2.2217x over previous
//
#include <hip/hip_runtime.h>

// ============================================================================
// Strategy: theta is batch-uniform => M = U^dag Z0 U is a fixed Hermitian op.
// Embedded state is a product state, so <psi|M|psi> = sum over 3^8 Pauli
// strings (I,Z,Y per wire) of alpha_P * prod_w {1, cos x_w, -sin x_w}.
// Prepass (7 tiny kernels) computes alpha via numeric Pauli-transfer matrices;
// main kernel does a 6561-term factorized contraction per batch element.
// ============================================================================

struct cpx { float re, im; };
__device__ __forceinline__ cpx cmul(cpx a, cpx b) {
    return {a.re * b.re - a.im * b.im, a.re * b.im + a.im * b.re};
}

__device__ __forceinline__ void get_pauli(int a, cpx P[2][2]) {
    cpx z{0.f, 0.f};
    P[0][0] = z; P[0][1] = z; P[1][0] = z; P[1][1] = z;
    switch (a) {
        case 0: P[0][0] = {1.f, 0.f}; P[1][1] = {1.f, 0.f}; break;   // I
        case 1: P[0][1] = {1.f, 0.f}; P[1][0] = {1.f, 0.f}; break;   // X
        case 2: P[0][1] = {0.f, -1.f}; P[1][0] = {0.f, 1.f}; break;  // Y
        case 3: P[0][0] = {1.f, 0.f}; P[1][1] = {-1.f, 0.f}; break;  // Z
    }
}

// ws float layout: A[65536] | B[65536] | TR[16*16] | CSGN[16] | CIDX[16 ints]
#define OFF_A    0
#define OFF_B    65536
#define OFF_TR   131072
#define OFF_CSGN 131328
#define OFF_CIDX 131344
#define WS_FLOATS_NEEDED 131360

// ---------------------------------------------------------------------------
// K0: init coefficient tensor to Z0; build per-gate 4x4 PTMs and CNOT table.
// Pauli string encoding: wire w occupies bits [2w, 2w+1]; codes 0=I,1=X,2=Y,3=Z.
// ---------------------------------------------------------------------------
__global__ void k_init(const float* __restrict__ theta, float* __restrict__ ws) {
    float* A = ws + OFF_A;
    for (int i = threadIdx.x; i < 65536; i += 256) A[i] = 0.f;
    __syncthreads();
    if (threadIdx.x == 0) A[3] = 1.f;  // Z on wire 0

    float* TR = ws + OFF_TR;
    float* CSGN = ws + OFF_CSGN;
    int* CIDX = (int*)(ws + OFF_CIDX);

    const int g = threadIdx.x;
    if (g < 16) {
        // Build Rot gate (PennyLane convention, matches reference) for layer l wire w.
        const int l = g >> 3, w = g & 7;
        const float phi = theta[(l * 8 + w) * 3 + 0];
        const float th  = theta[(l * 8 + w) * 3 + 1];
        const float om  = theta[(l * 8 + w) * 3 + 2];
        const float c = cosf(0.5f * th), s = sinf(0.5f * th);
        const float ps = 0.5f * (phi + om), ms = 0.5f * (phi - om);
        cpx G[2][2];
        G[0][0] = {c * cosf(ps), -c * sinf(ps)};   // e^{-i ps} c
        G[0][1] = {-s * cosf(ms), -s * sinf(ms)};  // -e^{+i ms} s
        G[1][0] = {s * cosf(ms), -s * sinf(ms)};   // e^{-i ms} s
        G[1][1] = {c * cosf(ps), c * sinf(ps)};    // e^{+i ps} c
        // PTM: T[a][b] = 0.5 * Re Tr(sigma_b * G^dag sigma_a G)
        for (int a = 0; a < 4; ++a) {
            cpx Pa[2][2]; get_pauli(a, Pa);
            cpx M1[2][2];  // sigma_a * G
            for (int i = 0; i < 2; ++i)
                for (int j = 0; j < 2; ++j) {
                    cpx acc{0.f, 0.f};
                    for (int k = 0; k < 2; ++k) {
                        cpx t = cmul(Pa[i][k], G[k][j]);
                        acc.re += t.re; acc.im += t.im;
                    }
                    M1[i][j] = acc;
                }
            cpx H[2][2];  // G^dag * M1
            for (int i = 0; i < 2; ++i)
                for (int j = 0; j < 2; ++j) {
                    cpx acc{0.f, 0.f};
                    for (int k = 0; k < 2; ++k) {
                        cpx gc{G[k][i].re, -G[k][i].im};
                        cpx t = cmul(gc, M1[k][j]);
                        acc.re += t.re; acc.im += t.im;
                    }
                    H[i][j] = acc;
                }
            for (int b = 0; b < 4; ++b) {
                cpx Pb[2][2]; get_pauli(b, Pb);
                float tr = 0.f;  // Re Tr(Pb * H)
                for (int i = 0; i < 2; ++i)
                    for (int j = 0; j < 2; ++j)
                        tr += Pb[i][j].re * H[j][i].re - Pb[i][j].im * H[j][i].im;
                TR[g * 16 + a * 4 + b] = 0.5f * tr;
            }
        }
    }
    if (g == 16) {
        // CNOT conjugation table (Clifford): pair (pc,pt) -> (pc',pt') with sign.
        const int perm[4] = {0, 1, 3, 2};  // CNOT basis permutation, |c,t> idx=2c+t
        for (int pc = 0; pc < 4; ++pc)
            for (int pt = 0; pt < 4; ++pt) {
                cpx Pc[2][2], Pt[2][2];
                get_pauli(pc, Pc); get_pauli(pt, Pt);
                cpx S[4][4];
                for (int i = 0; i < 2; ++i)
                    for (int j = 0; j < 2; ++j)
                        for (int k = 0; k < 2; ++k)
                            for (int l2 = 0; l2 < 2; ++l2)
                                S[2 * i + j][2 * k + l2] = cmul(Pc[i][k], Pt[j][l2]);
                cpx R[4][4];
                for (int r = 0; r < 4; ++r)
                    for (int c2 = 0; c2 < 4; ++c2)
                        R[r][c2] = S[perm[r]][perm[c2]];
                int bidx = 0; float bsgn = 1.f;
                for (int a = 0; a < 4; ++a)
                    for (int b2 = 0; b2 < 4; ++b2) {
                        cpx Pa[2][2], Pb[2][2];
                        get_pauli(a, Pa); get_pauli(b2, Pb);
                        float ov = 0.f;
                        for (int r = 0; r < 4; ++r)
                            for (int c2 = 0; c2 < 4; ++c2) {
                                cpx K = cmul(Pa[r >> 1][c2 >> 1], Pb[r & 1][c2 & 1]);
                                ov += K.re * R[r][c2].re + K.im * R[r][c2].im;
                            }
                        ov *= 0.25f;
                        if (ov > 0.5f) { bidx = a * 4 + b2; bsgn = 1.f; }
                        else if (ov < -0.5f) { bidx = a * 4 + b2; bsgn = -1.f; }
                    }
                CIDX[pc * 4 + pt] = bidx;
                CSGN[pc * 4 + pt] = bsgn;
            }
    }
}

// ---------------------------------------------------------------------------
// Ring conjugation: O -> Cring^dag O Cring. Ring applies CNOT(w, w+r) for
// w=0..7 in order, so conjugate by c7 first, down to c0. Pure permutation
// with sign (bijective scatter).
// ---------------------------------------------------------------------------
__global__ void k_ring(const float* __restrict__ in, float* __restrict__ out,
                       const float* __restrict__ ws, int r) {
    const int* CIDX = (const int*)(ws + OFF_CIDX);
    const float* CSGN = ws + OFF_CSGN;
    const int s = blockIdx.x * 256 + threadIdx.x;
    float v = in[s];
    int cur = s;
    float sg = 1.f;
    for (int w = 7; w >= 0; --w) {
        const int tw = (w + r) & 7;
        const int pc = (cur >> (2 * w)) & 3;
        const int pt = (cur >> (2 * tw)) & 3;
        const int q = pc * 4 + pt;
        const int nq = CIDX[q];
        sg *= CSGN[q];
        cur = (cur & ~((3 << (2 * w)) | (3 << (2 * tw))))
            | ((nq >> 2) << (2 * w)) | ((nq & 3) << (2 * tw));
    }
    out[cur] = sg * v;
}

// ---------------------------------------------------------------------------
// Rot-layer conjugation on 4 wires (hi=0: wires 0-3 at bits 0-7; hi=1: wires
// 4-7 at bits 8-15). Per-axis 4x4 PTM transform, tiled in LDS.
// c'_b = sum_a c_a T[a][b].
// ---------------------------------------------------------------------------
__global__ void k_rot(const float* __restrict__ in, float* __restrict__ out,
                      const float* __restrict__ ws, int layer, int hi) {
    __shared__ float b0[256], b1[256];
    const float* TR = ws + OFF_TR;
    const int o = blockIdx.x, i = threadIdx.x;
    const int s = hi ? ((i << 8) | o) : ((o << 8) | i);
    b0[i] = in[s];
    __syncthreads();
    float* cur = b0;
    float* nxt = b1;
    for (int lw = 0; lw < 4; ++lw) {
        const int w = lw + 4 * hi;
        const float* T = &TR[(layer * 8 + w) * 16];
        const int d = (i >> (2 * lw)) & 3;
        const int ib = i & ~(3 << (2 * lw));
        float nv = T[0 * 4 + d] * cur[ib]
                 + T[1 * 4 + d] * cur[ib | (1 << (2 * lw))]
                 + T[2 * 4 + d] * cur[ib | (2 << (2 * lw))]
                 + T[3 * 4 + d] * cur[ib | (3 << (2 * lw))];
        nxt[i] = nv;
        __syncthreads();
        float* t = cur; cur = nxt; nxt = t;
    }
    out[s] = cur[i];
}

// ---------------------------------------------------------------------------
// Main contraction: ev(b) = sum_{3^8 strings} alpha * prod_w m_w, with
// m_w in {1, cos x_w, -sin x_w} (I/Z/Y). alpha staged in LDS as 243 groups
// of 27 (padded to 28 for 16B-aligned ds_read_b128).
// ---------------------------------------------------------------------------
__global__ __launch_bounds__(256, 2) void k_main(const float* __restrict__ x,
                                                 const float* __restrict__ A,
                                                 float* __restrict__ out, int batch) {
    __shared__ __align__(16) float al[243 * 28];
    for (int idx = threadIdx.x; idx < 243 * 28; idx += 256) {
        const int g = idx / 28, j = idx % 28;
        float v = 0.f;
        if (j < 27) {
            int t3 = g * 27 + j;  // digits d0(wire0, slowest) .. d7(wire7, fastest)
            int s4 = 0;
#pragma unroll
            for (int w = 7; w >= 0; --w) {
                const int d = t3 % 3;
                t3 /= 3;
                const int code = (d == 0) ? 0 : ((d == 1) ? 3 : 2);  // I / Z / Y
                s4 |= code << (2 * w);
            }
            v = A[s4];
        }
        al[idx] = v;
    }
    __syncthreads();

    const int b = blockIdx.x * 256 + threadIdx.x;
    if (b >= batch) return;

    const float4* xp = (const float4*)(x + (size_t)b * 8);
    const float4 xa = xp[0], xb = xp[1];
    const float xs[8] = {xa.x, xa.y, xa.z, xa.w, xb.x, xb.y, xb.z, xb.w};
    float cw[8], msw[8];
#pragma unroll
    for (int w = 0; w < 8; ++w) {
        float sv, cv;
        __sincosf(xs[w], &sv, &cv);
        cw[w] = cv;
        msw[w] = -sv;
    }
    float f567[28];
    {
        const float F5[3] = {1.f, cw[5], msw[5]};
        const float F6[3] = {1.f, cw[6], msw[6]};
        const float F7[3] = {1.f, cw[7], msw[7]};
        int j = 0;
#pragma unroll
        for (int a = 0; a < 3; ++a)
#pragma unroll
            for (int b2 = 0; b2 < 3; ++b2)
#pragma unroll
                for (int c2 = 0; c2 < 3; ++c2) F567_SET: f567[j++] = F5[a] * F6[b2] * F7[c2];
        f567[27] = 0.f;
    }

    float acc = 0.f;
    int base = 0;
    for (int k0 = 0; k0 < 3; ++k0) {
        const float p0 = (k0 == 0) ? 1.f : ((k0 == 1) ? cw[0] : msw[0]);
        for (int k1 = 0; k1 < 3; ++k1) {
            const float p1 = p0 * ((k1 == 0) ? 1.f : ((k1 == 1) ? cw[1] : msw[1]));
            for (int k2 = 0; k2 < 3; ++k2) {
                const float p2 = p1 * ((k2 == 0) ? 1.f : ((k2 == 1) ? cw[2] : msw[2]));
#pragma unroll
                for (int k3 = 0; k3 < 3; ++k3) {
                    const float p3 = p2 * ((k3 == 0) ? 1.f : ((k3 == 1) ? cw[3] : msw[3]));
#pragma unroll
                    for (int k4 = 0; k4 < 3; ++k4) {
                        const float p4 = p3 * ((k4 == 0) ? 1.f : ((k4 == 1) ? cw[4] : msw[4]));
                        const float* Ap = &al[base];
                        float t0 = 0.f, t1 = 0.f, t2 = 0.f, t3v = 0.f;
#pragma unroll
                        for (int j = 0; j < 28; j += 4) {
                            t0 = fmaf(Ap[j + 0], f567[j + 0], t0);
                            t1 = fmaf(Ap[j + 1], f567[j + 1], t1);
                            t2 = fmaf(Ap[j + 2], f567[j + 2], t2);
                            t3v = fmaf(Ap[j + 3], f567[j + 3], t3v);
                        }
                        acc = fmaf((t0 + t1) + (t2 + t3v), p4, acc);
                        base += 28;
                    }
                }
            }
        }
    }
    out[b] = (acc + 1.f) * 0.5f;
}

// ============================================================================
// Fallback: round-1 direct statevector simulator (used if ws too small).
// ============================================================================
struct c32 { float x, y; };

__device__ __forceinline__ c32 shfl_xor_c(c32 v, int mask) {
    c32 r;
    r.x = __shfl_xor(v.x, mask, 64);
    r.y = __shfl_xor(v.y, mask, 64);
    return r;
}
__device__ __forceinline__ c32 cmadd2(c32 ga, c32 a, c32 gp, c32 p) {
    c32 n;
    n.x = ga.x * a.x - ga.y * a.y + gp.x * p.x - gp.y * p.y;
    n.y = ga.x * a.y + ga.y * a.x + gp.x * p.y + gp.y * p.x;
    return n;
}
__device__ __forceinline__ c32 rx_mix(float c, float s, c32 a, c32 p) {
    c32 n;
    n.x = c * a.x + s * p.y;
    n.y = c * a.y - s * p.x;
    return n;
}
__device__ __forceinline__ void apply_rx(c32 st[4], int lane, int bb, float c, float s) {
    if (bb < 6) {
#pragma unroll
        for (int r = 0; r < 4; ++r) {
            c32 p = shfl_xor_c(st[r], 1 << bb);
            st[r] = rx_mix(c, s, st[r], p);
        }
    } else if (bb == 6) {
        c32 n0 = rx_mix(c, s, st[0], st[1]);
        c32 n1 = rx_mix(c, s, st[1], st[0]);
        c32 n2 = rx_mix(c, s, st[2], st[3]);
        c32 n3 = rx_mix(c, s, st[3], st[2]);
        st[0] = n0; st[1] = n1; st[2] = n2; st[3] = n3;
    } else {
        c32 n0 = rx_mix(c, s, st[0], st[2]);
        c32 n2 = rx_mix(c, s, st[2], st[0]);
        c32 n1 = rx_mix(c, s, st[1], st[3]);
        c32 n3 = rx_mix(c, s, st[3], st[1]);
        st[0] = n0; st[1] = n1; st[2] = n2; st[3] = n3;
    }
}
__device__ __forceinline__ void apply_rot(c32 st[4], int lane, int bb,
                                          c32 g00, c32 g01, c32 g10, c32 g11) {
    if (bb < 6) {
#pragma unroll
        for (int r = 0; r < 4; ++r) {
            c32 p = shfl_xor_c(st[r], 1 << bb);
            bool hi = (lane >> bb) & 1;
            c32 ga, gp;
            ga.x = hi ? g11.x : g00.x;
            ga.y = hi ? g11.y : g00.y;
            gp.x = hi ? g10.x : g01.x;
            gp.y = hi ? g10.y : g01.y;
            st[r] = cmadd2(ga, st[r], gp, p);
        }
    } else if (bb == 6) {
        c32 n0 = cmadd2(g00, st[0], g01, st[1]);
        c32 n1 = cmadd2(g10, st[0], g11, st[1]);
        c32 n2 = cmadd2(g00, st[2], g01, st[3]);
        c32 n3 = cmadd2(g10, st[2], g11, st[3]);
        st[0] = n0; st[1] = n1; st[2] = n2; st[3] = n3;
    } else {
        c32 n0 = cmadd2(g00, st[0], g01, st[2]);
        c32 n2 = cmadd2(g10, st[0], g11, st[2]);
        c32 n1 = cmadd2(g00, st[1], g01, st[3]);
        c32 n3 = cmadd2(g10, st[1], g11, st[3]);
        st[0] = n0; st[1] = n1; st[2] = n2; st[3] = n3;
    }
}
__device__ __forceinline__ void cswap(bool c, c32& a, c32& b) {
    c32 t = a;
    a.x = c ? b.x : a.x; a.y = c ? b.y : a.y;
    b.x = c ? t.x : b.x; b.y = c ? t.y : b.y;
}
__device__ __forceinline__ void apply_cnot(c32 st[4], int lane, int bc, int bt) {
    if (bt < 6) {
        if (bc < 6) {
            bool ctrl = (lane >> bc) & 1;
#pragma unroll
            for (int r = 0; r < 4; ++r) {
                c32 p = shfl_xor_c(st[r], 1 << bt);
                st[r].x = ctrl ? p.x : st[r].x;
                st[r].y = ctrl ? p.y : st[r].y;
            }
        } else {
#pragma unroll
            for (int r = 0; r < 4; ++r) {
                if ((r >> (bc - 6)) & 1) st[r] = shfl_xor_c(st[r], 1 << bt);
            }
        }
    } else {
        if (bc < 6) {
            bool ctrl = (lane >> bc) & 1;
            if (bt == 6) { cswap(ctrl, st[0], st[1]); cswap(ctrl, st[2], st[3]); }
            else         { cswap(ctrl, st[0], st[2]); cswap(ctrl, st[1], st[3]); }
        } else {
            if (bc == 7 && bt == 6) { c32 t = st[2]; st[2] = st[3]; st[3] = t; }
            else if (bc == 6 && bt == 7) { c32 t = st[1]; st[1] = st[3]; st[3] = t; }
        }
    }
}
__global__ __launch_bounds__(256) void qsim_kernel(const float* __restrict__ x,
                                                   const float* __restrict__ theta,
                                                   float* __restrict__ out,
                                                   int batch) {
    __shared__ float rot[2 * 8 * 8];
    const int t = threadIdx.x;
    if (t < 16) {
        const int l = t >> 3, w = t & 7;
        const float phi = theta[(l * 8 + w) * 3 + 0];
        const float th  = theta[(l * 8 + w) * 3 + 1];
        const float om  = theta[(l * 8 + w) * 3 + 2];
        const float c = cosf(0.5f * th), s = sinf(0.5f * th);
        const float p = 0.5f * (phi + om), m = 0.5f * (phi - om);
        float* g = &rot[t * 8];
        g[0] = c * cosf(p);  g[1] = -c * sinf(p);
        g[2] = -s * cosf(m); g[3] = -s * sinf(m);
        g[4] = s * cosf(m);  g[5] = -s * sinf(m);
        g[6] = c * cosf(p);  g[7] = c * sinf(p);
    }
    __syncthreads();
    const int lane = t & 63;
    const int b = blockIdx.x * 4 + (t >> 6);
    if (b >= batch) return;
    float c8 = 0.f, s8 = 0.f;
    if (lane < 8) {
        const float xv = 0.5f * x[b * 8 + lane];
        c8 = cosf(xv); s8 = sinf(xv);
    }
    c32 st[4];
#pragma unroll
    for (int r = 0; r < 4; ++r) { st[r].x = 0.f; st[r].y = 0.f; }
    if (lane == 0) st[0].x = 1.f;
#pragma unroll
    for (int w = 0; w < 8; ++w) {
        const float c = __shfl(c8, w, 64);
        const float s = __shfl(s8, w, 64);
        apply_rx(st, lane, 7 - w, c, s);
    }
#pragma unroll
    for (int l = 0; l < 2; ++l) {
#pragma unroll
        for (int w = 0; w < 8; ++w) {
            const float* g = &rot[(l * 8 + w) * 8];
            c32 g00{g[0], g[1]}, g01{g[2], g[3]}, g10{g[4], g[5]}, g11{g[6], g[7]};
            apply_rot(st, lane, 7 - w, g00, g01, g10, g11);
        }
        const int rr = l + 1;
#pragma unroll
        for (int w = 0; w < 8; ++w) apply_cnot(st, lane, 7 - w, 7 - ((w + rr) & 7));
    }
    float v = st[0].x * st[0].x + st[0].y * st[0].y
            + st[1].x * st[1].x + st[1].y * st[1].y
            - st[2].x * st[2].x - st[2].y * st[2].y
            - st[3].x * st[3].x - st[3].y * st[3].y;
#pragma unroll
    for (int off = 32; off > 0; off >>= 1) v += __shfl_xor(v, off, 64);
    if (lane == 0) out[b] = (v + 1.f) * 0.5f;
}

// ============================================================================
extern "C" void kernel_launch(void* const* d_in, const int* in_sizes, int n_in,
                              void* d_out, int out_size, void* d_ws, size_t ws_size,
                              hipStream_t stream) {
    const float* x     = (const float*)d_in[0];
    const float* theta = (const float*)d_in[1];
    float* out = (float*)d_out;
    const int batch = in_sizes[0] / 8;

    if (ws_size >= (size_t)WS_FLOATS_NEEDED * 4 + 256) {
        float* ws = (float*)d_ws;
        float* A = ws + OFF_A;
        float* B = ws + OFF_B;
        k_init<<<dim3(1), dim3(256), 0, stream>>>(theta, ws);
        k_ring<<<dim3(256), dim3(256), 0, stream>>>(A, B, ws, 2);  // C2 (layer1 ring, r=2)
        k_rot <<<dim3(256), dim3(256), 0, stream>>>(B, A, ws, 1, 0);  // Rb wires 0-3
        k_rot <<<dim3(256), dim3(256), 0, stream>>>(A, B, ws, 1, 1);  // Rb wires 4-7
        k_ring<<<dim3(256), dim3(256), 0, stream>>>(B, A, ws, 1);  // C1 (layer0 ring, r=1)
        k_rot <<<dim3(256), dim3(256), 0, stream>>>(A, B, ws, 0, 0);  // Ra wires 0-3
        k_rot <<<dim3(256), dim3(256), 0, stream>>>(B, A, ws, 0, 1);  // Ra wires 4-7
        k_main<<<dim3((batch + 255) / 256), dim3(256), 0, stream>>>(x, A, out, batch);
    } else {
        // Fallback: direct statevector sim (verified round 1).
        qsim_kernel<<<dim3((batch + 3) / 4), dim3(256), 0, stream>>>(x, theta, out, batch);
    }
}